// Round 14
// baseline (699.064 us; speedup 1.0000x reference)
//
#include <hip/hip_runtime.h>
#include <cstddef>

// Problem constants (from reference setup_inputs)
static constexpr int NN   = 100000;   // nodes
static constexpr int NE   = 3200000;  // edges
static constexpr int CIN  = 512;
static constexpr int CHID = 40;
static constexpr int COUT = 20;

// LDS-histogram CSR build geometry
static constexpr int NCH    = 32;            // edge chunks
static constexpr int CHUNK_E = NE / NCH;     // 100000 edges per chunk (div by 4)
static constexpr int NRANGE = 8;             // node ranges
static constexpr int RANGE  = NN / NRANGE;   // 12500 nodes -> 50 KB LDS histogram

// clang native vector type: required by __builtin_nontemporal_load
// (HIP float4 is a class type and is rejected -- R9 compile error).
typedef float f32x4 __attribute__((ext_vector_type(4)));

// ---------------- CSR build (LDS histograms; NO memory-side atomics) ----------------
// R12 lesson: global-memory atomics execute at the TCC regardless of scope
// (WRITE_SIZE 112.3MB identical for device-scope and workgroup-scope).
// R13 measured: this LDS-histogram build removed the 149-167us atomic kernel
// from the profile entirely. FROZEN this round.

__global__ __launch_bounds__(1024) void k_histA(const int* __restrict__ dst,
                                                int* __restrict__ cntb) {
  __shared__ int hc[RANGE];  // 50 KB
  const int c  = blockIdx.x >> 3;    // chunk 0..31
  const int r0 = (blockIdx.x & 7) * RANGE;
  for (int i = threadIdx.x; i < RANGE; i += 1024) hc[i] = 0;
  __syncthreads();
  const int base = c * (CHUNK_E / 4);
  const int end  = base + CHUNK_E / 4;
  for (int i = base + (int)threadIdx.x; i < end; i += 1024) {
    const int4 d = ((const int4*)dst)[i];
    if ((unsigned)(d.x - r0) < (unsigned)RANGE) atomicAdd(&hc[d.x - r0], 1);
    if ((unsigned)(d.y - r0) < (unsigned)RANGE) atomicAdd(&hc[d.y - r0], 1);
    if ((unsigned)(d.z - r0) < (unsigned)RANGE) atomicAdd(&hc[d.z - r0], 1);
    if ((unsigned)(d.w - r0) < (unsigned)RANGE) atomicAdd(&hc[d.w - r0], 1);
  }
  __syncthreads();
  int* __restrict__ outp = cntb + (size_t)c * NN + r0;
  for (int i = threadIdx.x; i < RANGE; i += 1024) outp[i] = hc[i];
}

// per node: exclusive prefix across the 32 chunk-copies (in place) + total.
__global__ __launch_bounds__(256) void k_merge(int* __restrict__ cntb, int* __restrict__ cnt, int n) {
  const int i = blockIdx.x * 256 + threadIdx.x;
  if (i >= n) return;
  int s = 0;
#pragma unroll 8
  for (int b = 0; b < NCH; ++b) {
    int* p = cntb + (size_t)b * NN + i;
    const int t = *p;
    *p = s;
    s += t;
  }
  cnt[i] = s;
}

// block of 256 scans 1024 elements; writes per-element exclusive scan (within block),
// block totals, and fused dinv = rsqrt(deg) = rsqrt(cnt+1).
__global__ __launch_bounds__(256) void k_scanA(const int* __restrict__ cnt, int* __restrict__ excl,
                                               int* __restrict__ bsums, float* __restrict__ dinv, int n) {
  __shared__ int sdata[256];
  const int t = threadIdx.x;
  const int base = blockIdx.x * 1024 + t * 4;
  int v[4];
#pragma unroll
  for (int j = 0; j < 4; ++j) {
    const int i = base + j;
    v[j] = (i < n) ? cnt[i] : 0;
    if (i < n) dinv[i] = rsqrtf((float)(v[j] + 1));
  }
  const int s4 = v[0] + v[1] + v[2] + v[3];
  sdata[t] = s4;
  __syncthreads();
  for (int off = 1; off < 256; off <<= 1) {
    int val = 0;
    if (t >= off) val = sdata[t - off];
    __syncthreads();
    sdata[t] += val;
    __syncthreads();
  }
  int run = sdata[t] - s4;  // exclusive prefix of this thread's 4 items
#pragma unroll
  for (int j = 0; j < 4; ++j) {
    const int i = base + j;
    if (i < n) excl[i] = run;
    run += v[j];
  }
  if (t == 255) bsums[blockIdx.x] = sdata[255];
}

__global__ __launch_bounds__(256) void k_scanB(int* __restrict__ bsums, int nb) {
  __shared__ int sdata[256];
  const int t = threadIdx.x;
  const int v = (t < nb) ? bsums[t] : 0;
  sdata[t] = v;
  __syncthreads();
  for (int off = 1; off < 256; off <<= 1) {
    int val = 0;
    if (t >= off) val = sdata[t - off];
    __syncthreads();
    sdata[t] += val;
    __syncthreads();
  }
  if (t < nb) bsums[t] = sdata[t] - v;  // exclusive, in place
}

__global__ __launch_bounds__(256) void k_scanC(int* __restrict__ rowptr, const int* __restrict__ boff,
                                               int n, int n_edges) {
  const int i = blockIdx.x * 256 + threadIdx.x;
  if (i < n) rowptr[i] += boff[i >> 10];
  if (i == 0) rowptr[n] = n_edges;
}

// Pass B: re-read chunk, re-run the LDS histogram to assign local ranks,
// place edges: pos = rowptr[d] + cntb[c][d] (cross-chunk offset) + lds_rank.
__global__ __launch_bounds__(1024) void k_histFill(const int* __restrict__ src,
                                                   const int* __restrict__ dst,
                                                   const int* __restrict__ rowptr,
                                                   const int* __restrict__ cntb,
                                                   int* __restrict__ csr_src) {
  __shared__ int hc[RANGE];  // 50 KB
  const int c  = blockIdx.x >> 3;
  const int r0 = (blockIdx.x & 7) * RANGE;
  for (int i = threadIdx.x; i < RANGE; i += 1024) hc[i] = 0;
  __syncthreads();
  const int* __restrict__ cbo = cntb + (size_t)c * NN;
  const int base = c * (CHUNK_E / 4);
  const int end  = base + CHUNK_E / 4;
  for (int i = base + (int)threadIdx.x; i < end; i += 1024) {
    const int4 d = ((const int4*)dst)[i];
    const int4 s = ((const int4*)src)[i];
    if ((unsigned)(d.x - r0) < (unsigned)RANGE) {
      const int rk = atomicAdd(&hc[d.x - r0], 1);
      csr_src[rowptr[d.x] + cbo[d.x] + rk] = s.x;
    }
    if ((unsigned)(d.y - r0) < (unsigned)RANGE) {
      const int rk = atomicAdd(&hc[d.y - r0], 1);
      csr_src[rowptr[d.y] + cbo[d.y] + rk] = s.y;
    }
    if ((unsigned)(d.z - r0) < (unsigned)RANGE) {
      const int rk = atomicAdd(&hc[d.z - r0], 1);
      csr_src[rowptr[d.z] + cbo[d.z] + rk] = s.z;
    }
    if ((unsigned)(d.w - r0) < (unsigned)RANGE) {
      const int rk = atomicAdd(&hc[d.w - r0], 1);
      csr_src[rowptr[d.w] + cbo[d.w] + rk] = s.w;
    }
  }
}

// ---------------- GEMM 1: double-buffered K=64 pipeline ----------------
// R13: 149us, VALUBusy 20.9% (VALU work ~31us), Occupancy 38%, read stream
// only ~1.4 TB/s. Little's law: lockstep load->barrier->compute keeps ~1.5KB
// outstanding per CU (~1 TB/s cap at ~900cyc HBM latency). Fix: K=64 tiles,
// 2 x 16KB LDS buffers (32KB total, occupancy unchanged); per tile: issue
// next tile's 4 NT loads -> compute current buffer (640 FMAs cover latency)
// -> ds_write other buffer -> ONE barrier. Writers of buf[(t+1)&1] only
// conflict with readers in compute(t-1) -- impossible past the t-1 barrier.
// g = t>>6 wave-uniform (R10 lesson); k ascends 0..511 strictly ->
// bit-identical summation order (absmax 4.88e-4).
__global__ __launch_bounds__(256) void k_gemm1(const float* __restrict__ x, const float* __restrict__ W,
                                               float* __restrict__ h, int n) {
  __shared__ float xt[2][64 * 64];  // 2 x 16 KB; xt[0] reused as output staging [64][44]
  const int t  = threadIdx.x;
  const int nd = t & 63;                                   // node-in-tile (compute)
  const int g  = __builtin_amdgcn_readfirstlane(t >> 6);   // channel group 0..3 (wave-uniform)
  const int block0 = blockIdx.x * 64;

  // staging map per tile: 1024 f32x4 / 256 threads = 4 each;
  // iteration r: row = r*16 + srow, col c4 (16 lanes cover one 256B row seg).
  const int srow = t >> 4;   // 0..15
  const int c4   = t & 15;   // 0..15

  float acc[10];
#pragma unroll
  for (int j = 0; j < 10; ++j) acc[j] = 0.f;

  f32x4 v[4];
  // prologue: stage tile 0 into buf0
#pragma unroll
  for (int r = 0; r < 4; ++r) {
    const int row = r * 16 + srow;
    int gn = block0 + row;
    if (gn >= n) gn = n - 1;  // clamp: valid memory, store is guarded
    v[r] = __builtin_nontemporal_load(((const f32x4*)(x + (size_t)gn * CIN)) + c4);
  }
#pragma unroll
  for (int r = 0; r < 4; ++r) {
    const int row = r * 16 + srow;
    const int byte = row * 256 + ((c4 * 16) ^ ((row & 15) << 4));
    *(f32x4*)((char*)&xt[0][0] + byte) = v[r];
  }
  __syncthreads();  // tile 0 ready

  for (int kt = 0; kt < 8; ++kt) {
    if (kt < 7) {  // issue next tile's loads NOW; they fly during compute(kt)
#pragma unroll
      for (int r = 0; r < 4; ++r) {
        const int row = r * 16 + srow;
        int gn = block0 + row;
        if (gn >= n) gn = n - 1;
        v[r] = __builtin_nontemporal_load(
            ((const f32x4*)(x + (size_t)gn * CIN + (kt + 1) * 64)) + c4);
      }
    }

    // ---- compute: 64 k-values, 10 channels per thread
    const float* __restrict__ bufc = &xt[kt & 1][0];
    const float* __restrict__ Wg = W + (size_t)kt * 64 * CHID + g * 10;
#pragma unroll 4
    for (int k4 = 0; k4 < 16; ++k4) {
      const int byte = nd * 256 + ((k4 * 16) ^ ((nd & 15) << 4));
      const f32x4 xv = *(const f32x4*)((const char*)bufc + byte);
      const float* __restrict__ Wk = Wg + k4 * 4 * CHID;
#pragma unroll
      for (int j = 0; j < 10; ++j) acc[j] = fmaf(xv.x, Wk[j], acc[j]);
#pragma unroll
      for (int j = 0; j < 10; ++j) acc[j] = fmaf(xv.y, Wk[CHID + j], acc[j]);
#pragma unroll
      for (int j = 0; j < 10; ++j) acc[j] = fmaf(xv.z, Wk[2 * CHID + j], acc[j]);
#pragma unroll
      for (int j = 0; j < 10; ++j) acc[j] = fmaf(xv.w, Wk[3 * CHID + j], acc[j]);
    }

    if (kt < 7) {  // park next tile into the OTHER buffer; one barrier per tile
#pragma unroll
      for (int r = 0; r < 4; ++r) {
        const int row = r * 16 + srow;
        const int byte = row * 256 + ((c4 * 16) ^ ((row & 15) << 4));
        *(f32x4*)((char*)&xt[(kt + 1) & 1][0] + byte) = v[r];
      }
      __syncthreads();  // tile kt+1 ready; all waves past compute(kt)
    }
  }

  // ---- coalesced epilogue through LDS (xt[0]; safe: tile-7 readers use xt[1]) ----
#pragma unroll
  for (int j = 0; j < 10; ++j) xt[0][nd * 44 + g * 10 + j] = acc[j];
  __syncthreads();
  // 64 rows x 40 floats = 640 float4, contiguous across the block's h region
  for (int i = t; i < 640; i += 256) {
    const int row = i / 10;
    const int c   = i % 10;
    const int node = block0 + row;
    if (node < n)
      ((float4*)(h + (size_t)node * CHID))[c] = *(const float4*)&xt[0][row * 44 + c * 4];
  }
}

__global__ __launch_bounds__(256) void k_gemm2(const float* __restrict__ t1, const float* __restrict__ W,
                                               float* __restrict__ g, int n) {
  const int node = blockIdx.x * 256 + threadIdx.x;
  if (node >= n) return;
  const float4* __restrict__ r4 = (const float4*)(t1 + (size_t)node * CHID);
  float acc[COUT];
#pragma unroll
  for (int c = 0; c < COUT; ++c) acc[c] = 0.f;
#pragma unroll
  for (int kk = 0; kk < CHID / 4; ++kk) {
    const float4 xv = r4[kk];
    const float* __restrict__ Wk = W + kk * 4 * COUT;
#pragma unroll
    for (int c = 0; c < COUT; ++c) {
      float a = acc[c];
      a = fmaf(xv.x, Wk[c], a);
      a = fmaf(xv.y, Wk[COUT + c], a);
      a = fmaf(xv.z, Wk[2 * COUT + c], a);
      a = fmaf(xv.w, Wk[3 * COUT + c], a);
      acc[c] = a;
    }
  }
  float* __restrict__ o = g + (size_t)node * COUT;
#pragma unroll
  for (int c = 0; c < COUT; ++c) o[c] = acc[c];
}

// ---------------- CSR aggregation ----------------
// Layer 1 (CH=40): float2 channel-packing — 20 lanes/node, 3 nodes/wave.
__global__ __launch_bounds__(256) void k_agg40(const float* __restrict__ h, const int* __restrict__ rowptr,
                                               const int* __restrict__ csr_src, const float* __restrict__ dinv,
                                               const float* __restrict__ bias, float* __restrict__ out, int n) {
  const int wave = (blockIdx.x * 256 + (int)threadIdx.x) >> 6;
  const int lane = threadIdx.x & 63;
  const int sub  = lane / 20;   // 0..2 active; 3 => idle lanes 60..63
  const int cp   = lane % 20;   // channel pair: channels {2cp, 2cp+1}
  const int node = wave * 3 + sub;
  if (sub >= 3 || node >= n) return;
  const float2* __restrict__ h2 = (const float2*)h;
  const int r0 = rowptr[node];
  const int r1 = rowptr[node + 1];
  const float dv = dinv[node];
  const float self_w = dv * dv;  // self-loop norm = 1/deg
  float2 acc = h2[(size_t)node * 20 + cp];
  acc.x *= self_w;
  acc.y *= self_w;
  int i = r0;
  for (; i + 4 <= r1; i += 4) {
    const int s0 = csr_src[i + 0];
    const int s1 = csr_src[i + 1];
    const int s2 = csr_src[i + 2];
    const int s3 = csr_src[i + 3];
    const float w0 = dinv[s0] * dv;
    const float w1 = dinv[s1] * dv;
    const float w2 = dinv[s2] * dv;
    const float w3 = dinv[s3] * dv;
    const float2 g0 = h2[(size_t)s0 * 20 + cp];
    const float2 g1 = h2[(size_t)s1 * 20 + cp];
    const float2 g2 = h2[(size_t)s2 * 20 + cp];
    const float2 g3 = h2[(size_t)s3 * 20 + cp];
    acc.x = fmaf(g0.x, w0, acc.x); acc.y = fmaf(g0.y, w0, acc.y);
    acc.x = fmaf(g1.x, w1, acc.x); acc.y = fmaf(g1.y, w1, acc.y);
    acc.x = fmaf(g2.x, w2, acc.x); acc.y = fmaf(g2.y, w2, acc.y);
    acc.x = fmaf(g3.x, w3, acc.x); acc.y = fmaf(g3.y, w3, acc.y);
  }
  for (; i < r1; ++i) {
    const int s = csr_src[i];
    const float w = dinv[s] * dv;
    const float2 g = h2[(size_t)s * 20 + cp];
    acc.x = fmaf(g.x, w, acc.x);
    acc.y = fmaf(g.y, w, acc.y);
  }
  const float2 bv = ((const float2*)bias)[cp];
  float2 v;
  v.x = fmaxf(acc.x + bv.x, 0.f);  // ReLU (layer 1 only)
  v.y = fmaxf(acc.y + bv.y, 0.f);
  ((float2*)out)[(size_t)node * 20 + cp] = v;
}

// Layer 2 (CH=20): float2 packing — 10 lanes/node, 6 nodes/wave.
__global__ __launch_bounds__(256) void k_agg20(const float* __restrict__ h, const int* __restrict__ rowptr,
                                               const int* __restrict__ csr_src, const float* __restrict__ dinv,
                                               const float* __restrict__ bias, float* __restrict__ out, int n) {
  const int wave = (blockIdx.x * 256 + (int)threadIdx.x) >> 6;
  const int lane = threadIdx.x & 63;
  const int sub  = lane / 10;   // 0..5 active; 6 => idle lanes 60..63
  const int cp   = lane % 10;   // channel pair: channels {2cp, 2cp+1}
  const int node = wave * 6 + sub;
  if (sub >= 6 || node >= n) return;
  const float2* __restrict__ h2 = (const float2*)h;
  const int r0 = rowptr[node];
  const int r1 = rowptr[node + 1];
  const float dv = dinv[node];
  const float self_w = dv * dv;
  float2 acc = h2[(size_t)node * 10 + cp];
  acc.x *= self_w;
  acc.y *= self_w;
  int i = r0;
  for (; i + 4 <= r1; i += 4) {
    const int s0 = csr_src[i + 0];
    const int s1 = csr_src[i + 1];
    const int s2 = csr_src[i + 2];
    const int s3 = csr_src[i + 3];
    const float w0 = dinv[s0] * dv;
    const float w1 = dinv[s1] * dv;
    const float w2 = dinv[s2] * dv;
    const float w3 = dinv[s3] * dv;
    const float2 g0 = h2[(size_t)s0 * 10 + cp];
    const float2 g1 = h2[(size_t)s1 * 10 + cp];
    const float2 g2 = h2[(size_t)s2 * 10 + cp];
    const float2 g3 = h2[(size_t)s3 * 10 + cp];
    acc.x = fmaf(g0.x, w0, acc.x); acc.y = fmaf(g0.y, w0, acc.y);
    acc.x = fmaf(g1.x, w1, acc.x); acc.y = fmaf(g1.y, w1, acc.y);
    acc.x = fmaf(g2.x, w2, acc.x); acc.y = fmaf(g2.y, w2, acc.y);
    acc.x = fmaf(g3.x, w3, acc.x); acc.y = fmaf(g3.y, w3, acc.y);
  }
  for (; i < r1; ++i) {
    const int s = csr_src[i];
    const float w = dinv[s] * dv;
    const float2 g = h2[(size_t)s * 10 + cp];
    acc.x = fmaf(g.x, w, acc.x);
    acc.y = fmaf(g.y, w, acc.y);
  }
  const float2 bv = ((const float2*)bias)[cp];
  float2 v;
  v.x = acc.x + bv.x;
  v.y = acc.y + bv.y;
  ((float2*)out)[(size_t)node * 10 + cp] = v;
}

// ---------------- launch ----------------

extern "C" void kernel_launch(void* const* d_in, const int* in_sizes, int n_in,
                              void* d_out, int out_size, void* d_ws, size_t ws_size,
                              hipStream_t stream) {
  const float* x   = (const float*)d_in[0];
  const int*   ei  = (const int*)d_in[1];
  const float* W1  = (const float*)d_in[2];
  const float* b1  = (const float*)d_in[3];
  const float* W2  = (const float*)d_in[4];
  const float* b2  = (const float*)d_in[5];
  float* out = (float*)d_out;

  const int* srcp = ei;        // edge_index[0]
  const int* dstp = ei + NE;   // edge_index[1]

  // workspace layout (~59 MB; rank[] eliminated, cntb 12.8MB)
  char* ws = (char*)d_ws;
  size_t off = 0;
  auto take = [&](size_t bytes) -> char* {
    char* p = ws + off;
    off = (off + bytes + 255) & ~(size_t)255;
    return p;
  };
  int*   cnt     = (int*)take((size_t)NN * 4);
  int*   rowptr  = (int*)take((size_t)(NN + 1) * 4);
  float* dinv    = (float*)take((size_t)NN * 4);
  int*   bsums   = (int*)take(256 * 4);
  int*   cntb    = (int*)take((size_t)NCH * NN * 4);  // 12.8 MB chunk histograms
  int*   csr_src = (int*)take((size_t)NE * 4);
  float* h1      = (float*)take((size_t)NN * CHID * 4);
  float* t1      = (float*)take((size_t)NN * CHID * 4);
  float* g2      = h1;  // h1 dead after agg1; reuse for layer-2 GEMM output

  (void)in_sizes; (void)n_in; (void)out_size; (void)ws_size;

  const int nb = (NN + 1023) / 1024;  // 98

  k_histA<<<NCH * NRANGE, 1024, 0, stream>>>(dstp, cntb);
  k_merge<<<(NN + 255) / 256, 256, 0, stream>>>(cntb, cnt, NN);
  k_scanA<<<nb, 256, 0, stream>>>(cnt, rowptr, bsums, dinv, NN);
  k_scanB<<<1, 256, 0, stream>>>(bsums, nb);
  k_scanC<<<(NN + 255) / 256, 256, 0, stream>>>(rowptr, bsums, NN, NE);
  k_histFill<<<NCH * NRANGE, 1024, 0, stream>>>(srcp, dstp, rowptr, cntb, csr_src);

  k_gemm1<<<(NN + 63) / 64, 256, 0, stream>>>(x, W1, h1, NN);
  const int nwaves1 = (NN + 2) / 3;            // 3 nodes per wave
  k_agg40<<<(nwaves1 + 3) / 4, 256, 0, stream>>>(h1, rowptr, csr_src, dinv, b1, t1, NN);
  k_gemm2<<<(NN + 255) / 256, 256, 0, stream>>>(t1, W2, g2, NN);
  const int nwaves2 = (NN + 5) / 6;            // 6 nodes per wave
  k_agg20<<<(nwaves2 + 3) / 4, 256, 0, stream>>>(g2, rowptr, csr_src, dinv, b2, out, NN);
}

// Round 15
// 693.232 us; speedup vs baseline: 1.0084x; 1.0084x over previous
//
#include <hip/hip_runtime.h>
#include <cstddef>

// Problem constants (from reference setup_inputs)
static constexpr int NN   = 100000;   // nodes
static constexpr int NE   = 3200000;  // edges
static constexpr int CIN  = 512;
static constexpr int CHID = 40;
static constexpr int COUT = 20;

// LDS-histogram CSR build geometry
static constexpr int NCH    = 32;            // edge chunks
static constexpr int CHUNK_E = NE / NCH;     // 100000 edges per chunk (div by 4)
static constexpr int NRANGE = 8;             // node ranges
static constexpr int RANGE  = NN / NRANGE;   // 12500 nodes -> 50 KB LDS histogram

// clang native vector type (HIP float4 rejected by NT builtins -- R9 lesson)
typedef float f32x4 __attribute__((ext_vector_type(4)));

#define GLB_AS __attribute__((address_space(1)))
#define LDS_AS __attribute__((address_space(3)))

// ---------------- CSR build (LDS histograms; NO memory-side atomics) ----------------
// R12 lesson: global-memory atomics execute at the TCC regardless of scope.
// R13 measured: LDS-histogram build removed the 149-167us atomic kernel. FROZEN.

__global__ __launch_bounds__(1024) void k_histA(const int* __restrict__ dst,
                                                int* __restrict__ cntb) {
  __shared__ int hc[RANGE];  // 50 KB
  const int c  = blockIdx.x >> 3;    // chunk 0..31
  const int r0 = (blockIdx.x & 7) * RANGE;
  for (int i = threadIdx.x; i < RANGE; i += 1024) hc[i] = 0;
  __syncthreads();
  const int base = c * (CHUNK_E / 4);
  const int end  = base + CHUNK_E / 4;
  for (int i = base + (int)threadIdx.x; i < end; i += 1024) {
    const int4 d = ((const int4*)dst)[i];
    if ((unsigned)(d.x - r0) < (unsigned)RANGE) atomicAdd(&hc[d.x - r0], 1);
    if ((unsigned)(d.y - r0) < (unsigned)RANGE) atomicAdd(&hc[d.y - r0], 1);
    if ((unsigned)(d.z - r0) < (unsigned)RANGE) atomicAdd(&hc[d.z - r0], 1);
    if ((unsigned)(d.w - r0) < (unsigned)RANGE) atomicAdd(&hc[d.w - r0], 1);
  }
  __syncthreads();
  int* __restrict__ outp = cntb + (size_t)c * NN + r0;
  for (int i = threadIdx.x; i < RANGE; i += 1024) outp[i] = hc[i];
}

// per node: exclusive prefix across the 32 chunk-copies (in place) + total.
__global__ __launch_bounds__(256) void k_merge(int* __restrict__ cntb, int* __restrict__ cnt, int n) {
  const int i = blockIdx.x * 256 + threadIdx.x;
  if (i >= n) return;
  int s = 0;
#pragma unroll 8
  for (int b = 0; b < NCH; ++b) {
    int* p = cntb + (size_t)b * NN + i;
    const int t = *p;
    *p = s;
    s += t;
  }
  cnt[i] = s;
}

// block of 256 scans 1024 elements; fused dinv = rsqrt(cnt+1).
__global__ __launch_bounds__(256) void k_scanA(const int* __restrict__ cnt, int* __restrict__ excl,
                                               int* __restrict__ bsums, float* __restrict__ dinv, int n) {
  __shared__ int sdata[256];
  const int t = threadIdx.x;
  const int base = blockIdx.x * 1024 + t * 4;
  int v[4];
#pragma unroll
  for (int j = 0; j < 4; ++j) {
    const int i = base + j;
    v[j] = (i < n) ? cnt[i] : 0;
    if (i < n) dinv[i] = rsqrtf((float)(v[j] + 1));
  }
  const int s4 = v[0] + v[1] + v[2] + v[3];
  sdata[t] = s4;
  __syncthreads();
  for (int off = 1; off < 256; off <<= 1) {
    int val = 0;
    if (t >= off) val = sdata[t - off];
    __syncthreads();
    sdata[t] += val;
    __syncthreads();
  }
  int run = sdata[t] - s4;  // exclusive prefix of this thread's 4 items
#pragma unroll
  for (int j = 0; j < 4; ++j) {
    const int i = base + j;
    if (i < n) excl[i] = run;
    run += v[j];
  }
  if (t == 255) bsums[blockIdx.x] = sdata[255];
}

__global__ __launch_bounds__(256) void k_scanB(int* __restrict__ bsums, int nb) {
  __shared__ int sdata[256];
  const int t = threadIdx.x;
  const int v = (t < nb) ? bsums[t] : 0;
  sdata[t] = v;
  __syncthreads();
  for (int off = 1; off < 256; off <<= 1) {
    int val = 0;
    if (t >= off) val = sdata[t - off];
    __syncthreads();
    sdata[t] += val;
    __syncthreads();
  }
  if (t < nb) bsums[t] = sdata[t] - v;  // exclusive, in place
}

__global__ __launch_bounds__(256) void k_scanC(int* __restrict__ rowptr, const int* __restrict__ boff,
                                               int n, int n_edges) {
  const int i = blockIdx.x * 256 + threadIdx.x;
  if (i < n) rowptr[i] += boff[i >> 10];
  if (i == 0) rowptr[n] = n_edges;
}

// Pass B: re-read chunk, re-run LDS histogram for local ranks, place edges.
__global__ __launch_bounds__(1024) void k_histFill(const int* __restrict__ src,
                                                   const int* __restrict__ dst,
                                                   const int* __restrict__ rowptr,
                                                   const int* __restrict__ cntb,
                                                   int* __restrict__ csr_src) {
  __shared__ int hc[RANGE];  // 50 KB
  const int c  = blockIdx.x >> 3;
  const int r0 = (blockIdx.x & 7) * RANGE;
  for (int i = threadIdx.x; i < RANGE; i += 1024) hc[i] = 0;
  __syncthreads();
  const int* __restrict__ cbo = cntb + (size_t)c * NN;
  const int base = c * (CHUNK_E / 4);
  const int end  = base + CHUNK_E / 4;
  for (int i = base + (int)threadIdx.x; i < end; i += 1024) {
    const int4 d = ((const int4*)dst)[i];
    const int4 s = ((const int4*)src)[i];
    if ((unsigned)(d.x - r0) < (unsigned)RANGE) {
      const int rk = atomicAdd(&hc[d.x - r0], 1);
      csr_src[rowptr[d.x] + cbo[d.x] + rk] = s.x;
    }
    if ((unsigned)(d.y - r0) < (unsigned)RANGE) {
      const int rk = atomicAdd(&hc[d.y - r0], 1);
      csr_src[rowptr[d.y] + cbo[d.y] + rk] = s.y;
    }
    if ((unsigned)(d.z - r0) < (unsigned)RANGE) {
      const int rk = atomicAdd(&hc[d.z - r0], 1);
      csr_src[rowptr[d.z] + cbo[d.z] + rk] = s.z;
    }
    if ((unsigned)(d.w - r0) < (unsigned)RANGE) {
      const int rk = atomicAdd(&hc[d.w - r0], 1);
      csr_src[rowptr[d.w] + cbo[d.w] + rk] = s.w;
    }
  }
}

// ---------------- GEMM 1: global_load_lds staging (m97 pattern) ----------------
// R13/R14: three reg-staging schedules all pin at ~150us (VALU work 31us
// conserved) -- compiler sinks loads to their ds_write use; source-level
// pipelining is dead (matches guide m131-m141). Switch to the guide's
// biggest measured lever: __builtin_amdgcn_global_load_lds width=16
// (m151: +35% vs reg-staging at same tile). Wave issues 8 one-inst DMA
// loads, reaches barrier fast; staging flows HBM->LDS while other blocks'
// waves compute. LDS dest is linear (lane l -> base + l*16); the bank
// swizzle moves to the PRE-SWIZZLED GLOBAL col: lane loads col4 s^(row&31)
// so linear LDS holds data where the swizzled compute-read expects it
// (compute loop identical to R13; bit-identical summation order).
// aux=2 = CPol NT bit (gfx940 lineage): keeps the R11 victim-write fix.
// Discriminator: WRITE_SIZE stays ~15.6MB iff NT took.
__global__ __launch_bounds__(256) void k_gemm1(const float* __restrict__ x, const float* __restrict__ W,
                                               float* __restrict__ h, int n) {
  __shared__ float xt[64 * 128];  // 32 KB; reused as output staging [64][44]
  const int t    = threadIdx.x;
  const int nd   = t & 63;                                   // node-in-tile (compute)
  const int g    = __builtin_amdgcn_readfirstlane(t >> 6);   // wave 0..3 (wave-uniform)
  const int lane = t & 63;
  const int block0 = blockIdx.x * 64;

  // staging: wave g owns rows g*16..g*16+15; call j covers rows g*16+j*2+(lane>>5).
  // lane l -> LDS byte (g*16+j*2)*512 + l*16  (= row*512 + slot*16, slot=l&31).
  // slot s must hold global col4 s^(row&31)  -> pre-swizzled source address.
  const int sub = lane >> 5;   // 0/1
  const int s   = lane & 31;   // slot

  float acc[10];
#pragma unroll
  for (int j = 0; j < 10; ++j) acc[j] = 0.f;

  for (int kt = 0; kt < 4; ++kt) {
    if (kt) __syncthreads();  // previous tile fully consumed
#pragma unroll
    for (int j = 0; j < 8; ++j) {
      const int row = g * 16 + j * 2 + sub;
      int gn = block0 + row;
      if (gn >= n) gn = n - 1;  // clamp: valid memory, h-store is guarded
      const int c = s ^ (row & 31);  // pre-swizzled global col4
      const float* gp = x + (size_t)gn * CIN + kt * 128 + c * 4;
      float* lp = &xt[(g * 16 + j * 2) * 128];  // wave-uniform LDS base
      __builtin_amdgcn_global_load_lds((const GLB_AS void*)gp, (LDS_AS void*)lp,
                                       16, 0, 2 /*CPol NT*/);
    }
    __syncthreads();  // compiler drains vmcnt(0) before s_barrier -> tile ready

    // ---- compute: 128 k-values, 10 channels per thread (identical to R13)
    const float* __restrict__ Wg = W + (size_t)kt * 128 * CHID + g * 10;
#pragma unroll 4
    for (int k4 = 0; k4 < 32; ++k4) {
      const int byte = nd * 512 + ((k4 * 16) ^ ((nd & 31) << 4));
      const f32x4 xv = *(const f32x4*)((const char*)xt + byte);
      const float* __restrict__ Wk = Wg + k4 * 4 * CHID;
#pragma unroll
      for (int j = 0; j < 10; ++j) acc[j] = fmaf(xv.x, Wk[j], acc[j]);
#pragma unroll
      for (int j = 0; j < 10; ++j) acc[j] = fmaf(xv.y, Wk[CHID + j], acc[j]);
#pragma unroll
      for (int j = 0; j < 10; ++j) acc[j] = fmaf(xv.z, Wk[2 * CHID + j], acc[j]);
#pragma unroll
      for (int j = 0; j < 10; ++j) acc[j] = fmaf(xv.w, Wk[3 * CHID + j], acc[j]);
    }
  }

  // ---- coalesced epilogue through LDS ----
  __syncthreads();  // all waves done reading xt
#pragma unroll
  for (int j = 0; j < 10; ++j) xt[nd * 44 + g * 10 + j] = acc[j];
  __syncthreads();
  // 64 rows x 40 floats = 640 float4, contiguous across the block's h region
  for (int i = t; i < 640; i += 256) {
    const int row = i / 10;
    const int c   = i % 10;
    const int node = block0 + row;
    if (node < n)
      ((float4*)(h + (size_t)node * CHID))[c] = *(const float4*)&xt[row * 44 + c * 4];
  }
}

__global__ __launch_bounds__(256) void k_gemm2(const float* __restrict__ t1, const float* __restrict__ W,
                                               float* __restrict__ g, int n) {
  const int node = blockIdx.x * 256 + threadIdx.x;
  if (node >= n) return;
  const float4* __restrict__ r4 = (const float4*)(t1 + (size_t)node * CHID);
  float acc[COUT];
#pragma unroll
  for (int c = 0; c < COUT; ++c) acc[c] = 0.f;
#pragma unroll
  for (int kk = 0; kk < CHID / 4; ++kk) {
    const float4 xv = r4[kk];
    const float* __restrict__ Wk = W + kk * 4 * COUT;
#pragma unroll
    for (int c = 0; c < COUT; ++c) {
      float a = acc[c];
      a = fmaf(xv.x, Wk[c], a);
      a = fmaf(xv.y, Wk[COUT + c], a);
      a = fmaf(xv.z, Wk[2 * COUT + c], a);
      a = fmaf(xv.w, Wk[3 * COUT + c], a);
      acc[c] = a;
    }
  }
  float* __restrict__ o = g + (size_t)node * COUT;
#pragma unroll
  for (int c = 0; c < COUT; ++c) o[c] = acc[c];
}

// ---------------- CSR aggregation ----------------
// Layer 1 (CH=40): float2 channel-packing — 20 lanes/node, 3 nodes/wave.
__global__ __launch_bounds__(256) void k_agg40(const float* __restrict__ h, const int* __restrict__ rowptr,
                                               const int* __restrict__ csr_src, const float* __restrict__ dinv,
                                               const float* __restrict__ bias, float* __restrict__ out, int n) {
  const int wave = (blockIdx.x * 256 + (int)threadIdx.x) >> 6;
  const int lane = threadIdx.x & 63;
  const int sub  = lane / 20;   // 0..2 active; 3 => idle lanes 60..63
  const int cp   = lane % 20;   // channel pair: channels {2cp, 2cp+1}
  const int node = wave * 3 + sub;
  if (sub >= 3 || node >= n) return;
  const float2* __restrict__ h2 = (const float2*)h;
  const int r0 = rowptr[node];
  const int r1 = rowptr[node + 1];
  const float dv = dinv[node];
  const float self_w = dv * dv;  // self-loop norm = 1/deg
  float2 acc = h2[(size_t)node * 20 + cp];
  acc.x *= self_w;
  acc.y *= self_w;
  int i = r0;
  for (; i + 4 <= r1; i += 4) {
    const int s0 = csr_src[i + 0];
    const int s1 = csr_src[i + 1];
    const int s2 = csr_src[i + 2];
    const int s3 = csr_src[i + 3];
    const float w0 = dinv[s0] * dv;
    const float w1 = dinv[s1] * dv;
    const float w2 = dinv[s2] * dv;
    const float w3 = dinv[s3] * dv;
    const float2 g0 = h2[(size_t)s0 * 20 + cp];
    const float2 g1 = h2[(size_t)s1 * 20 + cp];
    const float2 g2 = h2[(size_t)s2 * 20 + cp];
    const float2 g3 = h2[(size_t)s3 * 20 + cp];
    acc.x = fmaf(g0.x, w0, acc.x); acc.y = fmaf(g0.y, w0, acc.y);
    acc.x = fmaf(g1.x, w1, acc.x); acc.y = fmaf(g1.y, w1, acc.y);
    acc.x = fmaf(g2.x, w2, acc.x); acc.y = fmaf(g2.y, w2, acc.y);
    acc.x = fmaf(g3.x, w3, acc.x); acc.y = fmaf(g3.y, w3, acc.y);
  }
  for (; i < r1; ++i) {
    const int s = csr_src[i];
    const float w = dinv[s] * dv;
    const float2 g = h2[(size_t)s * 20 + cp];
    acc.x = fmaf(g.x, w, acc.x);
    acc.y = fmaf(g.y, w, acc.y);
  }
  const float2 bv = ((const float2*)bias)[cp];
  float2 v;
  v.x = fmaxf(acc.x + bv.x, 0.f);  // ReLU (layer 1 only)
  v.y = fmaxf(acc.y + bv.y, 0.f);
  ((float2*)out)[(size_t)node * 20 + cp] = v;
}

// Layer 2 (CH=20): float2 packing — 10 lanes/node, 6 nodes/wave.
__global__ __launch_bounds__(256) void k_agg20(const float* __restrict__ h, const int* __restrict__ rowptr,
                                               const int* __restrict__ csr_src, const float* __restrict__ dinv,
                                               const float* __restrict__ bias, float* __restrict__ out, int n) {
  const int wave = (blockIdx.x * 256 + (int)threadIdx.x) >> 6;
  const int lane = threadIdx.x & 63;
  const int sub  = lane / 10;   // 0..5 active; 6 => idle lanes 60..63
  const int cp   = lane % 10;   // channel pair: channels {2cp, 2cp+1}
  const int node = wave * 6 + sub;
  if (sub >= 6 || node >= n) return;
  const float2* __restrict__ h2 = (const float2*)h;
  const int r0 = rowptr[node];
  const int r1 = rowptr[node + 1];
  const float dv = dinv[node];
  const float self_w = dv * dv;
  float2 acc = h2[(size_t)node * 10 + cp];
  acc.x *= self_w;
  acc.y *= self_w;
  int i = r0;
  for (; i + 4 <= r1; i += 4) {
    const int s0 = csr_src[i + 0];
    const int s1 = csr_src[i + 1];
    const int s2 = csr_src[i + 2];
    const int s3 = csr_src[i + 3];
    const float w0 = dinv[s0] * dv;
    const float w1 = dinv[s1] * dv;
    const float w2 = dinv[s2] * dv;
    const float w3 = dinv[s3] * dv;
    const float2 g0 = h2[(size_t)s0 * 10 + cp];
    const float2 g1 = h2[(size_t)s1 * 10 + cp];
    const float2 g2 = h2[(size_t)s2 * 10 + cp];
    const float2 g3 = h2[(size_t)s3 * 10 + cp];
    acc.x = fmaf(g0.x, w0, acc.x); acc.y = fmaf(g0.y, w0, acc.y);
    acc.x = fmaf(g1.x, w1, acc.x); acc.y = fmaf(g1.y, w1, acc.y);
    acc.x = fmaf(g2.x, w2, acc.x); acc.y = fmaf(g2.y, w2, acc.y);
    acc.x = fmaf(g3.x, w3, acc.x); acc.y = fmaf(g3.y, w3, acc.y);
  }
  for (; i < r1; ++i) {
    const int s = csr_src[i];
    const float w = dinv[s] * dv;
    const float2 g = h2[(size_t)s * 10 + cp];
    acc.x = fmaf(g.x, w, acc.x);
    acc.y = fmaf(g.y, w, acc.y);
  }
  const float2 bv = ((const float2*)bias)[cp];
  float2 v;
  v.x = acc.x + bv.x;
  v.y = acc.y + bv.y;
  ((float2*)out)[(size_t)node * 10 + cp] = v;
}

// ---------------- launch ----------------

extern "C" void kernel_launch(void* const* d_in, const int* in_sizes, int n_in,
                              void* d_out, int out_size, void* d_ws, size_t ws_size,
                              hipStream_t stream) {
  const float* x   = (const float*)d_in[0];
  const int*   ei  = (const int*)d_in[1];
  const float* W1  = (const float*)d_in[2];
  const float* b1  = (const float*)d_in[3];
  const float* W2  = (const float*)d_in[4];
  const float* b2  = (const float*)d_in[5];
  float* out = (float*)d_out;

  const int* srcp = ei;        // edge_index[0]
  const int* dstp = ei + NE;   // edge_index[1]

  // workspace layout (~59 MB)
  char* ws = (char*)d_ws;
  size_t off = 0;
  auto take = [&](size_t bytes) -> char* {
    char* p = ws + off;
    off = (off + bytes + 255) & ~(size_t)255;
    return p;
  };
  int*   cnt     = (int*)take((size_t)NN * 4);
  int*   rowptr  = (int*)take((size_t)(NN + 1) * 4);
  float* dinv    = (float*)take((size_t)NN * 4);
  int*   bsums   = (int*)take(256 * 4);
  int*   cntb    = (int*)take((size_t)NCH * NN * 4);  // 12.8 MB chunk histograms
  int*   csr_src = (int*)take((size_t)NE * 4);
  float* h1      = (float*)take((size_t)NN * CHID * 4);
  float* t1      = (float*)take((size_t)NN * CHID * 4);
  float* g2      = h1;  // h1 dead after agg1; reuse for layer-2 GEMM output

  (void)in_sizes; (void)n_in; (void)out_size; (void)ws_size;

  const int nb = (NN + 1023) / 1024;  // 98

  k_histA<<<NCH * NRANGE, 1024, 0, stream>>>(dstp, cntb);
  k_merge<<<(NN + 255) / 256, 256, 0, stream>>>(cntb, cnt, NN);
  k_scanA<<<nb, 256, 0, stream>>>(cnt, rowptr, bsums, dinv, NN);
  k_scanB<<<1, 256, 0, stream>>>(bsums, nb);
  k_scanC<<<(NN + 255) / 256, 256, 0, stream>>>(rowptr, bsums, NN, NE);
  k_histFill<<<NCH * NRANGE, 1024, 0, stream>>>(srcp, dstp, rowptr, cntb, csr_src);

  k_gemm1<<<(NN + 63) / 64, 256, 0, stream>>>(x, W1, h1, NN);
  const int nwaves1 = (NN + 2) / 3;            // 3 nodes per wave
  k_agg40<<<(nwaves1 + 3) / 4, 256, 0, stream>>>(h1, rowptr, csr_src, dinv, b1, t1, NN);
  k_gemm2<<<(NN + 255) / 256, 256, 0, stream>>>(t1, W2, g2, NN);
  const int nwaves2 = (NN + 5) / 6;            // 6 nodes per wave
  k_agg20<<<(nwaves2 + 3) / 4, 256, 0, stream>>>(g2, rowptr, csr_src, dinv, b2, out, NN);
}